// Round 2
// baseline (678.260 us; speedup 1.0000x reference)
//
#include <hip/hip_runtime.h>
#include <stdint.h>

typedef short short8 __attribute__((ext_vector_type(8)));
typedef float floatx4 __attribute__((ext_vector_type(4)));
typedef int int4v __attribute__((ext_vector_type(4)));

#define NB 4096
#define LL 110
#define DD 200
#define WPP 10
#define WFF 10
#define OUTW 110

#define MTI 7      // j tiles (112 rows, padded)
#define NTI 13     // e tiles (208 cols, padded)
#define KCH 7      // K chunks of 32 (224, padded)
#define LDSTR 232  // LDS row stride in bf16 elems (224 + 8 anti-conflict pad)

static __device__ __forceinline__ short f32_bf16_rn(float f) {
    uint32_t u = __float_as_uint(f);
    u += 0x7FFFu + ((u >> 16) & 1u);   // RTN-even
    return (short)(u >> 16);
}

// Pre-swizzle W (200x200 f32) into MFMA B-fragment layout, bf16, zero-padded:
// wswz[(kc*NTI + nt)*64 + lane][i] = W[kc*32 + (lane>>4)*8 + i][nt*16 + (lane&15)]
__global__ void EdgeAtt_wswz(const float* __restrict__ W, short* __restrict__ wswz) {
    const int nt = blockIdx.x / KCH;
    const int kc = blockIdx.x % KCH;
    const int l  = threadIdx.x;
    const int e  = nt * 16 + (l & 15);
    const int db = kc * 32 + (l >> 4) * 8;
    short8 v;
#pragma unroll
    for (int i = 0; i < 8; ++i) {
        int d = db + i;
        float x = (d < DD && e < DD) ? W[d * DD + e] : 0.0f;
        v[i] = f32_bf16_rn(x);
    }
    *(short8*)(wswz + ((size_t)(kc * NTI + nt) * 64 + l) * 8) = v;
}

__global__ __launch_bounds__(512) void EdgeAtt_fused(
    const float* __restrict__ nf, const int* __restrict__ lens,
    const short* __restrict__ wswz, float* __restrict__ out)
{
    __shared__ short nfb[112 * LDSTR];   // nf[b] as bf16, zero-padded
    __shared__ short ylds[112 * LDSTR];  // y = nf @ W as bf16, zero-padded
    const int b    = blockIdx.x;
    const int tid  = threadIdx.x;
    const int lane = tid & 63;
    const int wave = tid >> 6;           // 0..7
    const int len  = lens[b];

    // ---- phase 0: zero both LDS arrays (covers all pad regions) ----
    {
        int4v z = {0, 0, 0, 0};
        for (int i = tid; i < (112 * LDSTR) / 8; i += 512) {
            ((int4v*)nfb)[i]  = z;
            ((int4v*)ylds)[i] = z;
        }
    }
    __syncthreads();

    // ---- phase 1: load nf[b] (110x200 f32), convert to bf16 into LDS ----
    {
        const float4* src = (const float4*)(nf + (size_t)b * LL * DD);
        for (int idx = tid; idx < (LL * DD) / 4; idx += 512) {
            float4 v = src[idx];
            int j = (idx * 4) / DD;
            int d = (idx * 4) % DD;  // multiple of 4 (200 % 4 == 0)
            uint32_t lo = ((uint32_t)(uint16_t)f32_bf16_rn(v.y) << 16) | (uint16_t)f32_bf16_rn(v.x);
            uint32_t hi = ((uint32_t)(uint16_t)f32_bf16_rn(v.w) << 16) | (uint16_t)f32_bf16_rn(v.z);
            uint32_t* dst = (uint32_t*)&nfb[j * LDSTR + d];
            dst[0] = lo;
            dst[1] = hi;
        }
    }
    __syncthreads();

    // ---- phase 2: GEMM1  y[j,e] = sum_d nf[j,d] * W[d,e]  (M=112,N=208,K=224) ----
    {
        const int wm   = wave >> 2;          // 0..1 -> M tiles
        const int wn   = wave & 3;           // 0..3 -> N tiles
        const int arow = lane & 15;
        const int acol = (lane >> 4) * 8;
        for (int nt = wn; nt < NTI; nt += 4) {
            short8 bf[KCH];
#pragma unroll
            for (int kc = 0; kc < KCH; ++kc)
                bf[kc] = *(const short8*)(wswz + ((size_t)(kc * NTI + nt) * 64 + lane) * 8);
            for (int mt = wm; mt < MTI; mt += 2) {
                floatx4 acc = {0.f, 0.f, 0.f, 0.f};
                const short* abase = &nfb[(mt * 16 + arow) * LDSTR + acol];
#pragma unroll
                for (int kc = 0; kc < KCH; ++kc) {
                    short8 a = *(const short8*)(abase + kc * 32);
                    acc = __builtin_amdgcn_mfma_f32_16x16x32_bf16(a, bf[kc], acc, 0, 0, 0);
                }
                // D layout: row = (lane>>4)*4 + i, col = lane&15
                const int col = nt * 16 + (lane & 15);
                const int rb  = mt * 16 + (lane >> 4) * 4;
#pragma unroll
                for (int i = 0; i < 4; ++i)
                    ylds[(rb + i) * LDSTR + col] = f32_bf16_rn(acc[i]);
            }
        }
    }
    __syncthreads();

    // ---- phase 3: banded GEMM2 + softmax + store (waves 0..6: one j-tile each) ----
    if (wave < 7) {
        const int jt = wave;
        int kts[3];
#pragma unroll
        for (int t = 0; t < 3; ++t) {
            int kt = jt - 1 + t;
            kt = kt < 0 ? 0 : kt;
            kt = kt > (MTI - 1) ? (MTI - 1) : kt;
            kts[t] = kt;
        }
        floatx4 acc[3] = {{0,0,0,0},{0,0,0,0},{0,0,0,0}};
        const int r16  = lane & 15;
        const int acol = (lane >> 4) * 8;
#pragma unroll
        for (int kc = 0; kc < KCH; ++kc) {
            short8 a = *(const short8*)&ylds[(jt * 16 + r16) * LDSTR + kc * 32 + acol];
#pragma unroll
            for (int t = 0; t < 3; ++t) {
                short8 bb = *(const short8*)&nfb[(kts[t] * 16 + r16) * LDSTR + kc * 32 + acol];
                acc[t] = __builtin_amdgcn_mfma_f32_16x16x32_bf16(a, bb, acc[t], 0, 0, 0);
            }
        }
        // softmax over k within window [max(j-10,0), min(j+10,len-1)], row-parallel
        const int g  = lane >> 4;
        const int kl = lane & 15;
#pragma unroll
        for (int i = 0; i < 4; ++i) {
            const int j = jt * 16 + g * 4 + i;
            if (j >= LL) continue;               // uniform within 16-lane shuffle group
            const bool jv = (j < len);
            int slo = j - WPP; slo = slo < 0 ? 0 : slo;
            int shi = j + WFF; { int lm = len - 1; shi = shi > lm ? lm : shi; }
            float sv[3], ev[3];
            bool  kv[3];
            float m = -1e30f;
#pragma unroll
            for (int t = 0; t < 3; ++t) {
                int k = kts[t] * 16 + kl;
                bool tv = (t == 0) || (kts[t] != kts[t - 1]);   // dedupe clamped tiles
                kv[t] = jv && tv && (k >= slo) && (k <= shi);
                sv[t] = acc[t][i];
                if (kv[t]) m = fmaxf(m, sv[t]);
            }
#pragma unroll
            for (int o = 1; o < 16; o <<= 1) m = fmaxf(m, __shfl_xor(m, o, 64));
            float sum = 0.f;
#pragma unroll
            for (int t = 0; t < 3; ++t) {
                ev[t] = kv[t] ? __expf(sv[t] - m) : 0.f;
                sum += ev[t];
            }
#pragma unroll
            for (int o = 1; o < 16; o <<= 1) sum += __shfl_xor(sum, o, 64);
            const float inv = jv ? (1.0f / sum) : 0.0f;   // sum >= 1 when jv
            float* orow = out + ((size_t)b * LL + j) * OUTW;
#pragma unroll
            for (int kt = 0; kt < 7; ++kt) {
                int k = kt * 16 + kl;
                if (k >= OUTW) continue;
                float v = 0.0f;
                if      (kts[0] == kt) v = ev[0] * inv;
                else if (kts[1] == kt) v = ev[1] * inv;
                else if (kts[2] == kt) v = ev[2] * inv;
                orow[k] = v;
            }
        }
    }
}

extern "C" void kernel_launch(void* const* d_in, const int* in_sizes, int n_in,
                              void* d_out, int out_size, void* d_ws, size_t ws_size,
                              hipStream_t stream) {
    const float* nf   = (const float*)d_in[0];
    const int*   lens = (const int*)d_in[1];
    const float* W    = (const float*)d_in[2];
    short* wswz = (short*)d_ws;   // needs 7*13*64*8*2 = 93184 B
    float* out  = (float*)d_out;

    hipLaunchKernelGGL(EdgeAtt_wswz, dim3(KCH * NTI), dim3(64), 0, stream, W, wswz);
    hipLaunchKernelGGL(EdgeAtt_fused, dim3(NB), dim3(512), 0, stream, nf, lens, wswz, out);
}

// Round 3
// 664.734 us; speedup vs baseline: 1.0203x; 1.0203x over previous
//
#include <hip/hip_runtime.h>
#include <stdint.h>

typedef short short8 __attribute__((ext_vector_type(8)));
typedef float floatx4 __attribute__((ext_vector_type(4)));
typedef int int4v __attribute__((ext_vector_type(4)));

#define NB 4096
#define LL 110
#define DD 200
#define WPP 10
#define WFF 10
#define OUTW 110

#define NTI 13     // e tiles (208 cols, padded)
#define KCH 7      // K chunks of 32 (224, padded)
#define LDSTR 232  // LDS row stride in bf16 elems (224 + 8 anti-conflict pad)

#define NFROWS 80  // max nf-window rows per half-block (5 tiles)
#define YROWS 64   // max y rows per half-block (4 tiles)

static __device__ __forceinline__ short f32_bf16_rn(float f) {
    uint32_t u = __float_as_uint(f);
    u += 0x7FFFu + ((u >> 16) & 1u);   // RTN-even
    return (short)(u >> 16);
}

// Pre-swizzle W (200x200 f32) into MFMA B-fragment layout, bf16, zero-padded:
// wswz[(kc*NTI + nt)*64 + lane][i] = W[kc*32 + (lane>>4)*8 + i][nt*16 + (lane&15)]
__global__ void EdgeAtt_wswz(const float* __restrict__ W, short* __restrict__ wswz) {
    const int nt = blockIdx.x / KCH;
    const int kc = blockIdx.x % KCH;
    const int l  = threadIdx.x;
    const int e  = nt * 16 + (l & 15);
    const int db = kc * 32 + (l >> 4) * 8;
    short8 v;
#pragma unroll
    for (int i = 0; i < 8; ++i) {
        int d = db + i;
        float x = (d < DD && e < DD) ? W[d * DD + e] : 0.0f;
        v[i] = f32_bf16_rn(x);
    }
    *(short8*)(wswz + ((size_t)(kc * NTI + nt) * 64 + l) * 8) = v;
}

// One block per (b, j-half). h=0: j tiles 0..3 (rows 0..63), nf window tiles 0..4
// (rows 0..79). h=1: j tiles 4..6 (rows 64..109), nf window tiles 3..6 (rows 48..111).
// 65.25 KB LDS -> 2 blocks/CU so load/compute/store phases overlap across blocks.
__global__ __launch_bounds__(512, 4) void EdgeAtt_fused(
    const float* __restrict__ nf, const int* __restrict__ lens,
    const short* __restrict__ wswz, float* __restrict__ out)
{
    __shared__ short nfb[NFROWS * LDSTR];   // nf window as bf16, zero-padded
    __shared__ short ylds[YROWS * LDSTR];   // y = nf @ W as bf16, zero-padded
    const int b    = blockIdx.x >> 1;
    const int h    = blockIdx.x & 1;
    const int tid  = threadIdx.x;
    const int lane = tid & 63;
    const int wave = tid >> 6;              // 0..7
    const int len  = lens[b];

    const int base  = h ? 48 : 0;           // global nf row of nfb[0]
    const int nrows = h ? 64 : 80;          // nf-window rows
    const int j0    = h ? 64 : 0;           // global j of ylds[0]
    const int njt   = h ? 3  : 4;           // j tiles this block

    // ---- phase 0: zero LDS (covers K-pad cols and tail rows) ----
    {
        int4v z = {0, 0, 0, 0};
        for (int i = tid; i < (NFROWS * LDSTR) / 8; i += 512) ((int4v*)nfb)[i] = z;
        for (int i = tid; i < (YROWS * LDSTR) / 8; i += 512)  ((int4v*)ylds)[i] = z;
    }
    __syncthreads();

    // ---- phase 1: load nf window (f32), convert to bf16 into LDS ----
    {
        const float4* src = (const float4*)(nf + (size_t)b * LL * DD);
        const int nf4 = nrows * (DD / 4);
        for (int idx = tid; idx < nf4; idx += 512) {
            int rl = idx / (DD / 4);
            int d  = (idx % (DD / 4)) * 4;
            int rg = base + rl;
            if (rg < LL) {
                float4 v = src[rg * (DD / 4) + d / 4];
                uint32_t lo = ((uint32_t)(uint16_t)f32_bf16_rn(v.y) << 16) | (uint16_t)f32_bf16_rn(v.x);
                uint32_t hi = ((uint32_t)(uint16_t)f32_bf16_rn(v.w) << 16) | (uint16_t)f32_bf16_rn(v.z);
                uint32_t* dst = (uint32_t*)&nfb[rl * LDSTR + d];
                dst[0] = lo;
                dst[1] = hi;
            }
        }
    }
    __syncthreads();

    // ---- phase 2: GEMM1  y[j,e] = sum_d nf[j,d] * W[d,e] ----
    // Each wave owns one local j-tile (mt_l); A-fragments cached in regs across nt.
    if (wave < 2 * njt) {
        const int mt_l = wave % njt;
        const int wn   = wave / njt;        // nt parity
        const int rowA = (j0 - base) + mt_l * 16 + (lane & 15);
        const int acol = (lane >> 4) * 8;
        short8 af[KCH];
#pragma unroll
        for (int kc = 0; kc < KCH; ++kc)
            af[kc] = *(const short8*)&nfb[rowA * LDSTR + kc * 32 + acol];
        for (int nt = wn; nt < NTI; nt += 2) {
            floatx4 acc = {0.f, 0.f, 0.f, 0.f};
#pragma unroll
            for (int kc = 0; kc < KCH; ++kc) {
                short8 bf = *(const short8*)(wswz + ((size_t)(kc * NTI + nt) * 64 + lane) * 8);
                acc = __builtin_amdgcn_mfma_f32_16x16x32_bf16(af[kc], bf, acc, 0, 0, 0);
            }
            // D layout: row = (lane>>4)*4 + i, col = lane&15
            const int col = nt * 16 + (lane & 15);
            const int rb  = mt_l * 16 + (lane >> 4) * 4;
#pragma unroll
            for (int i = 0; i < 4; ++i)
                ylds[(rb + i) * LDSTR + col] = f32_bf16_rn(acc[i]);
        }
    }
    __syncthreads();

    // ---- phase 3: banded GEMM2 + softmax + store ----
    if (wave < njt) {
        const int jt_g = j0 / 16 + wave;    // global j tile
        const int ktb  = base / 16;         // global tile idx of nfb tile 0
        int kts[3];
#pragma unroll
        for (int t = 0; t < 3; ++t) {
            int kt = jt_g - 1 + t;
            kt = kt < 0 ? 0 : kt;
            kt = kt > 6 ? 6 : kt;
            kts[t] = kt;                    // global tile indices, all within window
        }
        floatx4 acc[3] = {{0,0,0,0},{0,0,0,0},{0,0,0,0}};
        const int r16  = lane & 15;
        const int acol = (lane >> 4) * 8;
#pragma unroll
        for (int kc = 0; kc < KCH; ++kc) {
            short8 a = *(const short8*)&ylds[(wave * 16 + r16) * LDSTR + kc * 32 + acol];
#pragma unroll
            for (int t = 0; t < 3; ++t) {
                short8 bb = *(const short8*)&nfb[((kts[t] - ktb) * 16 + r16) * LDSTR + kc * 32 + acol];
                acc[t] = __builtin_amdgcn_mfma_f32_16x16x32_bf16(a, bb, acc[t], 0, 0, 0);
            }
        }
        // softmax over k within window [max(j-10,0), min(j+10,len-1)], row-parallel
        const int g  = lane >> 4;
        const int kl = lane & 15;
#pragma unroll
        for (int i = 0; i < 4; ++i) {
            const int j = jt_g * 16 + g * 4 + i;
            if (j >= LL) continue;          // uniform within 16-lane shuffle group
            const bool jv = (j < len);
            int slo = j - WPP; slo = slo < 0 ? 0 : slo;
            int shi = j + WFF; { int lm = len - 1; shi = shi > lm ? lm : shi; }
            float sv[3], ev[3];
            bool  kv[3];
            float m = -1e30f;
#pragma unroll
            for (int t = 0; t < 3; ++t) {
                int k = kts[t] * 16 + kl;
                bool tv = (t == 0) || (kts[t] != kts[t - 1]);   // dedupe clamped tiles
                kv[t] = jv && tv && (k >= slo) && (k <= shi);
                sv[t] = acc[t][i];
                if (kv[t]) m = fmaxf(m, sv[t]);
            }
#pragma unroll
            for (int o = 1; o < 16; o <<= 1) m = fmaxf(m, __shfl_xor(m, o, 64));
            float sum = 0.f;
#pragma unroll
            for (int t = 0; t < 3; ++t) {
                ev[t] = kv[t] ? __expf(sv[t] - m) : 0.f;
                sum += ev[t];
            }
#pragma unroll
            for (int o = 1; o < 16; o <<= 1) sum += __shfl_xor(sum, o, 64);
            const float inv = jv ? (1.0f / sum) : 0.0f;   // sum >= 1 when jv
            float* orow = out + ((size_t)b * LL + j) * OUTW;
#pragma unroll
            for (int kt = 0; kt < 7; ++kt) {
                int k = kt * 16 + kl;
                if (k >= OUTW) continue;
                float v = 0.0f;
                if      (kts[0] == kt) v = ev[0] * inv;
                else if (kts[1] == kt) v = ev[1] * inv;
                else if (kts[2] == kt) v = ev[2] * inv;
                orow[k] = v;
            }
        }
    }
}

extern "C" void kernel_launch(void* const* d_in, const int* in_sizes, int n_in,
                              void* d_out, int out_size, void* d_ws, size_t ws_size,
                              hipStream_t stream) {
    const float* nf   = (const float*)d_in[0];
    const int*   lens = (const int*)d_in[1];
    const float* W    = (const float*)d_in[2];
    short* wswz = (short*)d_ws;   // needs 7*13*64*8*2 = 93184 B
    float* out  = (float*)d_out;

    hipLaunchKernelGGL(EdgeAtt_wswz, dim3(KCH * NTI), dim3(64), 0, stream, W, wswz);
    hipLaunchKernelGGL(EdgeAtt_fused, dim3(NB * 2), dim3(512), 0, stream, nf, lens, wswz, out);
}

// Round 6
// 623.371 us; speedup vs baseline: 1.0881x; 1.0664x over previous
//
#include <hip/hip_runtime.h>
#include <stdint.h>

typedef short short8 __attribute__((ext_vector_type(8)));
typedef float floatx4 __attribute__((ext_vector_type(4)));
typedef int int4v __attribute__((ext_vector_type(4)));
typedef unsigned int uint;

#define NB 4096
#define LL 110
#define DD 200
#define WPP 10
#define WFF 10
#define OUTW 110

#define NTI 13     // e tiles (208 cols, padded)
#define KCH 7      // K chunks of 32 (224, padded)

static __device__ __forceinline__ short f32_bf16_rn(float f) {
    uint32_t u = __float_as_uint(f);
    u += 0x7FFFu + ((u >> 16) & 1u);   // RTN-even
    return (short)(u >> 16);
}
static __device__ __forceinline__ uint pack2bf(float lo, float hi) {
    return ((uint)(unsigned short)f32_bf16_rn(hi) << 16) | (unsigned short)f32_bf16_rn(lo);
}

// Pre-swizzle W (200x200 f32) into MFMA fragment layout, bf16, zero-padded:
// wswz[(kc*NTI + nt)*64 + lane][i] = W[kc*32 + (lane>>4)*8 + i][nt*16 + (lane&15)]
// Serves as B-frag for y=nf@W AND as A-frag for the transposed form y^T = W^T @ nf^T.
__global__ void EdgeAtt_wswz(const float* __restrict__ W, short* __restrict__ wswz) {
    const int nt = blockIdx.x / KCH;
    const int kc = blockIdx.x % KCH;
    const int l  = threadIdx.x;
    const int e  = nt * 16 + (l & 15);
    const int db = kc * 32 + (l >> 4) * 8;
    short8 v;
#pragma unroll
    for (int i = 0; i < 8; ++i) {
        int d = db + i;
        float x = (d < DD && e < DD) ? W[d * DD + e] : 0.0f;
        v[i] = f32_bf16_rn(x);
    }
    *(short8*)(wswz + ((size_t)(kc * NTI + nt) * 64 + l) * 8) = v;
}

// Load nf row-fragment directly from global: lane holds nf[rt*16 + (lane&15)][kc*32 + (lane>>4)*8 + i]
// (rows clamped to LL-1; columns >= DD zeroed). Works as B-frag for both GEMMs.
static __device__ __forceinline__ short8 ld_nf_frag(const float* __restrict__ nf,
                                                    int b, int rt, int kc, int g, int r) {
    short8 s = {0, 0, 0, 0, 0, 0, 0, 0};
    const int cb = kc * 32 + g * 8;
    if (cb < DD) {                       // data-local divergence only (no cross-lane inside)
        int row = rt * 16 + r;
        row = row > (LL - 1) ? (LL - 1) : row;
        const float* p = nf + ((size_t)b * LL + row) * DD + cb;
        float4 a = *(const float4*)p;
        float4 c = *(const float4*)(p + 4);
        s[0] = f32_bf16_rn(a.x); s[1] = f32_bf16_rn(a.y);
        s[2] = f32_bf16_rn(a.z); s[3] = f32_bf16_rn(a.w);
        s[4] = f32_bf16_rn(c.x); s[5] = f32_bf16_rn(c.y);
        s[6] = f32_bf16_rn(c.z); s[7] = f32_bf16_rn(c.w);
    }
    return s;
}

// One WAVE per (b, j-tile). 16 waves/block; only barrier is after the one-time
// W-stage into LDS. Each wave: GEMM1' (y^T fragments via MFMA, W from LDS, nf from
// global) -> in-register lane-transpose (shfl) -> banded GEMM2 -> softmax -> store.
__global__ __launch_bounds__(1024) void EdgeAtt_fused(
    const float* __restrict__ nf, const int* __restrict__ lens,
    const short* __restrict__ wswz, float* __restrict__ out)
{
    __shared__ short wlds[KCH * NTI * 64 * 8];   // 93184 B, persistent W fragments
    const int tid = threadIdx.x;

    // ---- stage wswz -> LDS (once per block) ----
    for (int idx = tid; idx < KCH * NTI * 64; idx += 1024)
        ((short8*)wlds)[idx] = ((const short8*)wswz)[idx];
    __syncthreads();

    const int lane = tid & 63;
    const int wave = tid >> 6;
    const int unit = blockIdx.x * 16 + wave;     // 0 .. 28671
    const int b    = unit / 7;
    const int jt   = unit % 7;
    const int g    = lane >> 4;
    const int r    = lane & 15;
    const int len  = lens[b];

    // ---- nf j-row fragments (reused as GEMM1' B and GEMM2 middle-tile B) ----
    short8 jf[KCH];
#pragma unroll
    for (int kc = 0; kc < KCH; ++kc)
        jf[kc] = ld_nf_frag(nf, b, jt, kc, g, r);

    // ---- GEMM1': D'[e][j] = sum_d W[d][e] * nf[j][d]  (A = wswz frag, B = jf) ----
    // acc[nt] lane layout: e = nt*16 + g*4 + i, j = jt*16 + r
    floatx4 acc[NTI];
#pragma unroll
    for (int nt = 0; nt < NTI; ++nt) acc[nt] = (floatx4){0.f, 0.f, 0.f, 0.f};
#pragma unroll
    for (int kc = 0; kc < KCH; ++kc) {
#pragma unroll
        for (int nt = 0; nt < NTI; ++nt) {
            short8 wf = *(const short8*)&wlds[((kc * NTI + nt) * 64 + lane) * 8];
            acc[nt] = __builtin_amdgcn_mfma_f32_16x16x32_bf16(wf, jf[kc], acc[nt], 0, 0, 0);
        }
    }

    // ---- banded GEMM2 fused with the y lane-transpose ----
    int kts[3];
#pragma unroll
    for (int t = 0; t < 3; ++t) {
        int kt = jt - 1 + t;
        kt = kt < 0 ? 0 : kt;
        kt = kt > 6 ? 6 : kt;
        kts[t] = kt;
    }
    floatx4 acc2[3] = {{0,0,0,0},{0,0,0,0},{0,0,0,0}};
    const int src0 = (((2 * g) & 3) << 4) | r;       // source lane for dwords 0,1
    const int src1 = (((2 * g + 1) & 3) << 4) | r;   // source lane for dwords 2,3
    const bool lohalf = (g < 2);
#pragma unroll
    for (int kc = 0; kc < KCH; ++kc) {
        // A2 frag: lane holds y[j = jt*16 + r][e = kc*32 + g*8 + ii], ii=0..7.
        // Source element e lives at lane ((e%16)>>2)<<4 | r in acc[e>>4].
        const int nlo = 2 * kc;
        const int nhi = (kc < 6) ? (2 * kc + 1) : 12;   // kc==6 pad handled below
        uint plo0 = pack2bf(acc[nlo][0], acc[nlo][1]);
        uint plo1 = pack2bf(acc[nlo][2], acc[nlo][3]);
        uint phi0 = pack2bf(acc[nhi][0], acc[nhi][1]);
        uint phi1 = pack2bf(acc[nhi][2], acc[nhi][3]);
        // ALL shuffles executed unconditionally at full wave scope (ds_bpermute is
        // convergent: putting it on the arms of a lane-divergent ternary made clang
        // emit a divergent branch, and bpermute reads from exec-masked-off lanes are
        // undefined -> round-4 absmax 0.65). Select AFTER the shuffles (v_cndmask).
        uint l0 = (uint)__shfl((int)plo0, src0);
        uint l1 = (uint)__shfl((int)plo1, src0);
        uint l2 = (uint)__shfl((int)plo0, src1);
        uint l3 = (uint)__shfl((int)plo1, src1);
        uint h0 = (uint)__shfl((int)phi0, src0);
        uint h1 = (uint)__shfl((int)phi1, src0);
        uint h2 = (uint)__shfl((int)phi0, src1);
        uint h3 = (uint)__shfl((int)phi1, src1);
        const bool pad = (kc == 6) && (g >= 2);         // e >= 208
        uint d0 = pad ? 0u : (lohalf ? l0 : h0);
        uint d1 = pad ? 0u : (lohalf ? l1 : h1);
        uint d2 = pad ? 0u : (lohalf ? l2 : h2);
        uint d3 = pad ? 0u : (lohalf ? l3 : h3);
        int4v a2i; a2i[0] = (int)d0; a2i[1] = (int)d1; a2i[2] = (int)d2; a2i[3] = (int)d3;
        short8 a2 = *(short8*)&a2i;
#pragma unroll
        for (int t = 0; t < 3; ++t) {
            short8 bf;
            if (kts[t] == jt) bf = jf[kc];              // wave-uniform branch
            else              bf = ld_nf_frag(nf, b, kts[t], kc, g, r);
            acc2[t] = __builtin_amdgcn_mfma_f32_16x16x32_bf16(a2, bf, acc2[t], 0, 0, 0);
        }
    }

    // ---- softmax over k in window [max(j-10,0), min(j+10,len-1)] + store ----
    const int kl = r;
#pragma unroll
    for (int i = 0; i < 4; ++i) {
        const int j = jt * 16 + g * 4 + i;
        if (j >= LL) continue;               // uniform within each 16-lane shuffle group
        const bool jv = (j < len);
        int slo = j - WPP; slo = slo < 0 ? 0 : slo;
        int shi = j + WFF; { int lm = len - 1; shi = shi > lm ? lm : shi; }
        float sv[3], ev[3];
        bool  kv[3];
        float m = -1e30f;
#pragma unroll
        for (int t = 0; t < 3; ++t) {
            int k = kts[t] * 16 + kl;
            bool tv = (t == 0) || (kts[t] != kts[t - 1]);   // dedupe clamped tiles
            kv[t] = jv && tv && (k >= slo) && (k <= shi);
            sv[t] = acc2[t][i];
            if (kv[t]) m = fmaxf(m, sv[t]);
        }
#pragma unroll
        for (int o = 1; o < 16; o <<= 1) m = fmaxf(m, __shfl_xor(m, o, 64));
        float sum = 0.f;
#pragma unroll
        for (int t = 0; t < 3; ++t) {
            ev[t] = kv[t] ? __expf(sv[t] - m) : 0.f;
            sum += ev[t];
        }
#pragma unroll
        for (int o = 1; o < 16; o <<= 1) sum += __shfl_xor(sum, o, 64);
        const float inv = jv ? (1.0f / sum) : 0.0f;   // sum >= 1 when jv
        float* orow = out + ((size_t)b * LL + j) * OUTW;
#pragma unroll
        for (int kt = 0; kt < 7; ++kt) {
            int k = kt * 16 + kl;
            if (k >= OUTW) continue;
            float v = 0.0f;
            if      (kts[0] == kt) v = ev[0] * inv;
            else if (kts[1] == kt) v = ev[1] * inv;
            else if (kts[2] == kt) v = ev[2] * inv;
            orow[k] = v;
        }
    }
}

extern "C" void kernel_launch(void* const* d_in, const int* in_sizes, int n_in,
                              void* d_out, int out_size, void* d_ws, size_t ws_size,
                              hipStream_t stream) {
    const float* nf   = (const float*)d_in[0];
    const int*   lens = (const int*)d_in[1];
    const float* W    = (const float*)d_in[2];
    short* wswz = (short*)d_ws;   // needs 7*13*64*8*2 = 93184 B
    float* out  = (float*)d_out;

    hipLaunchKernelGGL(EdgeAtt_wswz, dim3(KCH * NTI), dim3(64), 0, stream, W, wswz);
    // 4096 b * 7 j-tiles = 28672 wave-units / 16 waves per block = 1792 blocks
    hipLaunchKernelGGL(EdgeAtt_fused, dim3(1792), dim3(1024), 0, stream, nf, lens, wswz, out);
}